// Round 2
// baseline (307.832 us; speedup 1.0000x reference)
//
#include <hip/hip_runtime.h>
#include <hip/hip_bf16.h>

// SelfAttentionLayer: B=64 S=512 E=512 H=8 D=64
// Round 8: identical to round 7 (resubmit — container infra failure, no
// bench data). qkv_gemm/outproj: 2-phase double-buffered LDS pipeline
// (stage next K-chunk before computing current; ONE barrier per K-step
// whose implicit vmcnt(0) drain lands after the MFMA phase). Q/K and
// outproj use swapped MFMA operand order (mfma(B,A)) so each lane holds
// 4 consecutive output columns -> ushort4/float4 packed stores. V path
// unchanged. attn_kernel unchanged from round 6 (verified passing).

#define Bn 64
#define Sn 512
#define En 512
#define Hn 8
#define Dn 64

typedef __attribute__((ext_vector_type(8))) short s8v;   // 8 bf16 = 4 VGPRs
typedef __attribute__((ext_vector_type(4))) float f4v;   // 4 fp32 acc

__device__ __forceinline__ unsigned short f2bf(float f) {
    union { float f; unsigned int u; } v; v.f = f;
    unsigned int u = v.u;
    u += 0x7fffu + ((u >> 16) & 1u);   // round-to-nearest-even
    return (unsigned short)(u >> 16);
}

__device__ __forceinline__ void async16(const unsigned short* g, unsigned short* l) {
    __builtin_amdgcn_global_load_lds((const __attribute__((address_space(1))) void*)g,
                                     (__attribute__((address_space(3))) void*)l, 16, 0, 0);
}
__device__ __forceinline__ void async4(const float* g, float* l) {
    __builtin_amdgcn_global_load_lds((const __attribute__((address_space(1))) void*)g,
                                     (__attribute__((address_space(3))) void*)l, 4, 0, 0);
}

// ---------------------------------------------------------------- prep_h
__global__ __launch_bounds__(256) void prep_h(const float* __restrict__ x,
                                              const float* __restrict__ BE,
                                              unsigned short* __restrict__ hbf) {
    int i = (blockIdx.x * 256 + threadIdx.x) * 4;
    int se = i % (Sn * En);
    float4 a = *(const float4*)(x + i);
    float4 b = *(const float4*)(BE + se);
    ushort4 o;
    o.x = f2bf(a.x + b.x); o.y = f2bf(a.y + b.y);
    o.z = f2bf(a.z + b.z); o.w = f2bf(a.w + b.w);
    *(ushort4*)(hbf + i) = o;
}

// ---------------------------------------------------------------- prep_w
__global__ __launch_bounds__(256) void prep_w(const float* __restrict__ WQ,
                                              const float* __restrict__ WK,
                                              const float* __restrict__ WV,
                                              const float* __restrict__ WO,
                                              unsigned short* __restrict__ Wqkvt,
                                              unsigned short* __restrict__ WOt) {
    int idx = blockIdx.x * 256 + threadIdx.x;
    const int NW = 3 * Hn * Dn * En;                   // 786432
    if (idx < NW) {
        int e = idx & 511;
        int d = (idx >> 9) & 63;
        int h = (idx >> 15) & 7;
        int m = idx >> 18;
        const float* W = (m == 0) ? WQ : (m == 1) ? WK : WV;
        Wqkvt[idx] = f2bf(W[(h * En + e) * Dn + d]);   // [m][h][d][e]
    } else {
        int j = idx - NW;
        int n = j & 511;
        int e = j >> 9;
        WOt[j] = f2bf(WO[n * En + e]);                  // WO_t[e][hd]
    }
}

// ---------------------------------------------------------------- qkv_gemm
// C[32768,1536] = hbf[32768,512] x Wqkvt^T. grid (12 nb, 256 mb), 256 thr.
// 2-phase dbuf: STAGE(next) || compute(cur); one barrier per K-step.
// nb<8 (Q,K): swapped mfma(B,A) -> lane holds d0..d0+3 -> ushort4 stores.
// nb>=8 (V): unswapped -> lane holds s0..s0+3 -> ushort4 stores along s.
__global__ __launch_bounds__(256) void qkv_gemm(const unsigned short* __restrict__ hbf,
                                                const unsigned short* __restrict__ Wqkvt,
                                                unsigned short* __restrict__ Qo,
                                                unsigned short* __restrict__ Ko,
                                                unsigned short* __restrict__ Vt) {
    int nb = blockIdx.x, mb = blockIdx.y;
    __shared__ __align__(16) unsigned short At[2][128 * 64];
    __shared__ __align__(16) unsigned short Bt[2][128 * 64];
    int tid = threadIdx.x;
    int w = tid >> 6, lane = tid & 63, quad = lane >> 4, l16 = lane & 15;
    int wr = w >> 1, wc = w & 1;
    int lrow = lane >> 3;
    int lseg = ((lane & 7) ^ lrow) * 8;
    bool swapQK = (nb < 8);

    f4v acc[4][4];
#pragma unroll
    for (int i = 0; i < 4; i++)
#pragma unroll
        for (int n = 0; n < 4; n++) acc[i][n] = (f4v){0.f, 0.f, 0.f, 0.f};

    const unsigned short* Ag = hbf + (size_t)mb * 128 * 512;
    const unsigned short* Bg = Wqkvt + (size_t)nb * 128 * 512;

    // prologue: stage chunk 0 into buffer 0
#pragma unroll
    for (int i = 0; i < 4; i++) {
        int r0 = w * 32 + i * 8;
        async16(Ag + (r0 + lrow) * 512 + lseg, &At[0][r0 * 64]);
        async16(Bg + (r0 + lrow) * 512 + lseg, &Bt[0][r0 * 64]);
    }
    __syncthreads();                               // vmcnt(0) drain + barrier

    int cur = 0;
    for (int kc = 0; kc < 8; kc++) {
        if (kc < 7) {                              // stage next chunk into buf^1
            int nxt = cur ^ 1;
#pragma unroll
            for (int i = 0; i < 4; i++) {
                int r0 = w * 32 + i * 8;
                async16(Ag + (r0 + lrow) * 512 + (kc + 1) * 64 + lseg, &At[nxt][r0 * 64]);
                async16(Bg + (r0 + lrow) * 512 + (kc + 1) * 64 + lseg, &Bt[nxt][r0 * 64]);
            }
        }
#pragma unroll
        for (int ks = 0; ks < 2; ks++) {
            int sw = ((ks * 4 + quad) ^ (l16 & 7)) * 8;
            s8v a[4], b[4];
#pragma unroll
            for (int i = 0; i < 4; i++)
                a[i] = *(const s8v*)&At[cur][(wr * 64 + i * 16 + l16) * 64 + sw];
#pragma unroll
            for (int n = 0; n < 4; n++)
                b[n] = *(const s8v*)&Bt[cur][(wc * 64 + n * 16 + l16) * 64 + sw];
            if (swapQK) {
#pragma unroll
                for (int i = 0; i < 4; i++)
#pragma unroll
                    for (int n = 0; n < 4; n++)
                        acc[i][n] = __builtin_amdgcn_mfma_f32_16x16x32_bf16(b[n], a[i], acc[i][n], 0, 0, 0);
            } else {
#pragma unroll
                for (int i = 0; i < 4; i++)
#pragma unroll
                    for (int n = 0; n < 4; n++)
                        acc[i][n] = __builtin_amdgcn_mfma_f32_16x16x32_bf16(a[i], b[n], acc[i][n], 0, 0, 0);
            }
        }
        if (kc < 7) __syncthreads();               // drains next-chunk loads too
        cur ^= 1;
    }

    int mat = nb >> 2;
    int h = (nb & 3) * 2 + wc;
    int b = mb >> 2;
    int s0 = (mb & 3) * 128 + wr * 64;
    const float qscale = 0.06375873f;   // log2(e)/sqrt(512): scale + exp->exp2 fold

    if (mat < 2) {
        // swapped layout: acc[i][n][r] -> d = n*16 + quad*4 + r, s = s0 + i*16 + l16
        unsigned short* op = (mat == 0) ? Qo : Ko;
        float sc = (mat == 0) ? qscale : 1.0f;
#pragma unroll
        for (int i = 0; i < 4; i++)
#pragma unroll
            for (int n = 0; n < 4; n++) {
                int s = s0 + i * 16 + l16;
                int d0 = n * 16 + quad * 4;
                ushort4 pk;
                pk.x = f2bf(acc[i][n][0] * sc);
                pk.y = f2bf(acc[i][n][1] * sc);
                pk.z = f2bf(acc[i][n][2] * sc);
                pk.w = f2bf(acc[i][n][3] * sc);
                *(ushort4*)&op[(size_t)((b * Hn + h) * Sn + s) * Dn + d0] = pk;
            }
    } else {
        // unswapped: V transposed Vt[b][h][d][s], packed along s
#pragma unroll
        for (int i = 0; i < 4; i++)
#pragma unroll
            for (int n = 0; n < 4; n++) {
                int d = n * 16 + l16;
                int s = s0 + i * 16 + quad * 4;
                ushort4 pk;
                pk.x = f2bf(acc[i][n][0]); pk.y = f2bf(acc[i][n][1]);
                pk.z = f2bf(acc[i][n][2]); pk.w = f2bf(acc[i][n][3]);
                *(ushort4*)&Vt[(size_t)((b * Hn + h) * Dn + d) * Sn + s] = pk;
            }
    }
}

// ---------------------------------------------------------------- attention
// grid (2 qhalf, 512 bh), 256 thr (4 waves). Wave w owns strips i=0..3
// (16 queries each of this block's 256-query half). S^T form:
//   sacc = mfma(A=K_frag, B=Q_frag): C rows = keys (key = n*16+quad*4+r),
//   col = query l16.
//   -> P packed uint2 -> b64 LDS writes, logical [query][key] swizzled
//   -> PV: A=P (b128), B=V^T rows; C rows = queries, cols = d.
__global__ __launch_bounds__(256) void attn_kernel(const unsigned short* __restrict__ Q,
                                                   const unsigned short* __restrict__ K,
                                                   const unsigned short* __restrict__ Vt,
                                                   const float* __restrict__ mask,
                                                   unsigned short* __restrict__ attn) {
    int qhalf = blockIdx.x, bh = blockIdx.y;
    int h = bh & 7, b = bh >> 3;
    __shared__ __align__(16) unsigned short Kc[64 * 64];        // [key][d] swizzled
    __shared__ __align__(16) unsigned short Vc[64 * 64];        // [d][key] swizzled
    __shared__ __align__(16) unsigned short Ps[4][4 * 16 * 64]; // [wave][strip][q][key]
    __shared__ float maskv[64];
    int tid = threadIdx.x;
    int w = tid >> 6, lane = tid & 63, quad = lane >> 4, l16 = lane & 15;
    int l7 = l16 & 7;

    const unsigned short* Qg = Q + (size_t)(bh * Sn + qhalf * 256) * Dn;
    const unsigned short* Kg = K + (size_t)(bh * Sn) * Dn;
    const unsigned short* Vg = Vt + (size_t)(bh * Dn) * Sn;

    // Q frags (A/B lane layouts identical), registers, whole kernel
    s8v aq[4][2];
#pragma unroll
    for (int i = 0; i < 4; i++)
#pragma unroll
        for (int ks = 0; ks < 2; ks++)
            aq[i][ks] = *(const s8v*)&Qg[((w * 4 + i) * 16 + l16) * 64 + ks * 32 + quad * 8];

    f4v acc[4][4];
    float psum[4] = {0.f, 0.f, 0.f, 0.f};
#pragma unroll
    for (int i = 0; i < 4; i++)
#pragma unroll
        for (int n = 0; n < 4; n++) acc[i][n] = (f4v){0.f, 0.f, 0.f, 0.f};

    // staging: each async16 covers 8 rows (64 lanes x 16B); wave w rows w*16..+15
    int srow0 = w * 16 + (lane >> 3);
    int srow1 = srow0 + 8;
    int gseg0 = ((lane & 7) ^ (srow0 & 7)) * 8;   // global seg so LDS[p] = g ^ (row&7)
    int gseg1 = ((lane & 7) ^ (srow1 & 7)) * 8;
    unsigned short* kdst0 = &Kc[(w * 16) * 64];
    unsigned short* kdst1 = &Kc[(w * 16 + 8) * 64];
    unsigned short* vdst0 = &Vc[(w * 16) * 64];
    unsigned short* vdst1 = &Vc[(w * 16 + 8) * 64];

    unsigned short* Pw = Ps[w];
    int wbase = l16 * 64 + (quad & 1) * 4;        // P write: row l16 + sub-offset
    const float cM = -1.4426950409e10f;           // -1e10 * log2(e)

    for (int kc = 0; kc < 8; kc++) {
        __syncthreads();                          // all waves done with prev chunk
        async16(Kg + (kc * 64 + srow0) * 64 + gseg0, kdst0);
        async16(Kg + (kc * 64 + srow1) * 64 + gseg1, kdst1);
        async16(Vg + srow0 * 512 + kc * 64 + gseg0, vdst0);
        async16(Vg + srow1 * 512 + kc * 64 + gseg1, vdst1);
        if (w == 0) async4(mask + b * Sn + kc * 64 + lane, maskv);
        __syncthreads();                          // vmcnt drained -> chunk ready

        // ---- S^T = K Q^T per key-tile n; bk shared across all 4 strips ----
#pragma unroll
        for (int n = 0; n < 4; n++) {
            s8v bk0 = *(const s8v*)&Kc[(n * 16 + l16) * 64 + (quad ^ l7) * 8];
            s8v bk1 = *(const s8v*)&Kc[(n * 16 + l16) * 64 + ((4 + quad) ^ l7) * 8];
            float4 mv = *(const float4*)&maskv[n * 16 + quad * 4];
            float m0 = mv.x * cM, m1 = mv.y * cM, m2 = mv.z * cM, m3 = mv.w * cM;
            int wseg = ((n * 2 + (quad >> 1)) ^ l7) * 8;
            f4v sacc[4];
#pragma unroll
            for (int i = 0; i < 4; i++) {
                sacc[i] = __builtin_amdgcn_mfma_f32_16x16x32_bf16(
                              bk0, aq[i][0], (f4v){0.f, 0.f, 0.f, 0.f}, 0, 0, 0);
                sacc[i] = __builtin_amdgcn_mfma_f32_16x16x32_bf16(
                              bk1, aq[i][1], sacc[i], 0, 0, 0);
            }
#pragma unroll
            for (int i = 0; i < 4; i++) {
                unsigned int u0 = __float_as_uint(__builtin_amdgcn_exp2f(sacc[i][0] + m0));
                unsigned int u1 = __float_as_uint(__builtin_amdgcn_exp2f(sacc[i][1] + m1));
                unsigned int u2 = __float_as_uint(__builtin_amdgcn_exp2f(sacc[i][2] + m2));
                unsigned int u3 = __float_as_uint(__builtin_amdgcn_exp2f(sacc[i][3] + m3));
                psum[i] += __uint_as_float(u0 & 0xffff0000u) + __uint_as_float(u1 & 0xffff0000u)
                         + __uint_as_float(u2 & 0xffff0000u) + __uint_as_float(u3 & 0xffff0000u);
                uint2 pk;
                pk.x = (u0 >> 16) | (u1 & 0xffff0000u);
                pk.y = (u2 >> 16) | (u3 & 0xffff0000u);
                *(uint2*)&Pw[(i << 10) + wbase + wseg] = pk;
            }
        }
        // Ps is wave-private; DS ops in-order per wave -> no barrier needed.

        // ---- O += P V : ks-outer, ap/bv shared across strips ----
#pragma unroll
        for (int ks = 0; ks < 2; ks++) {
            int sw = ((ks * 4 + quad) ^ l7) * 8;
            s8v ap[4];
#pragma unroll
            for (int i = 0; i < 4; i++)
                ap[i] = *(const s8v*)&Pw[(i << 10) + l16 * 64 + sw];
#pragma unroll
            for (int n = 0; n < 4; n++) {
                s8v bv = *(const s8v*)&Vc[(n * 16 + l16) * 64 + sw];
#pragma unroll
                for (int i = 0; i < 4; i++)
                    acc[i][n] = __builtin_amdgcn_mfma_f32_16x16x32_bf16(ap[i], bv, acc[i][n], 0, 0, 0);
            }
        }
    }

    // deferred normalization: psum[i] is quad-partial for query l16
#pragma unroll
    for (int i = 0; i < 4; i++) {
        float s = psum[i];
        s += __shfl_xor(s, 16, 64);
        s += __shfl_xor(s, 32, 64);               // every lane: total for query l16
        float inv[4];
#pragma unroll
        for (int r = 0; r < 4; r++)
            inv[r] = 1.0f / __shfl(s, quad * 4 + r, 64);
#pragma unroll
        for (int n = 0; n < 4; n++)
#pragma unroll
            for (int r = 0; r < 4; r++) {
                int query = qhalf * 256 + (w * 4 + i) * 16 + quad * 4 + r;
                int col = h * 64 + n * 16 + l16;
                attn[(size_t)(b * Sn + query) * (Hn * Dn) + col] = f2bf(acc[i][n][r] * inv[r]);
            }
    }
}

// ---------------------------------------------------------------- outproj
// out[32768,512] = attn[32768,512] x WOt^T, fp32 out. grid (4 nb, 256 mb).
// 2-phase dbuf + swapped mfma(B,A): lane holds 4 consecutive cols -> float4.
__global__ __launch_bounds__(256) void outproj(const unsigned short* __restrict__ attn,
                                               const unsigned short* __restrict__ WOt,
                                               float* __restrict__ out) {
    int nb = blockIdx.x, mb = blockIdx.y;
    __shared__ __align__(16) unsigned short At[2][128 * 64];
    __shared__ __align__(16) unsigned short Bt[2][128 * 64];
    int tid = threadIdx.x;
    int w = tid >> 6, lane = tid & 63, quad = lane >> 4, l16 = lane & 15;
    int wr = w >> 1, wc = w & 1;
    int lrow = lane >> 3;
    int lseg = ((lane & 7) ^ lrow) * 8;

    f4v acc[4][4];
#pragma unroll
    for (int i = 0; i < 4; i++)
#pragma unroll
        for (int n = 0; n < 4; n++) acc[i][n] = (f4v){0.f, 0.f, 0.f, 0.f};

    const unsigned short* Ag = attn + (size_t)mb * 128 * 512;
    const unsigned short* Bg = WOt + (size_t)nb * 128 * 512;

    // prologue: stage chunk 0
#pragma unroll
    for (int i = 0; i < 4; i++) {
        int r0 = w * 32 + i * 8;
        async16(Ag + (r0 + lrow) * 512 + lseg, &At[0][r0 * 64]);
        async16(Bg + (r0 + lrow) * 512 + lseg, &Bt[0][r0 * 64]);
    }
    __syncthreads();

    int cur = 0;
    for (int kc = 0; kc < 8; kc++) {
        if (kc < 7) {
            int nxt = cur ^ 1;
#pragma unroll
            for (int i = 0; i < 4; i++) {
                int r0 = w * 32 + i * 8;
                async16(Ag + (r0 + lrow) * 512 + (kc + 1) * 64 + lseg, &At[nxt][r0 * 64]);
                async16(Bg + (r0 + lrow) * 512 + (kc + 1) * 64 + lseg, &Bt[nxt][r0 * 64]);
            }
        }
#pragma unroll
        for (int ks = 0; ks < 2; ks++) {
            int sw = ((ks * 4 + quad) ^ (l16 & 7)) * 8;
            s8v a[4], b[4];
#pragma unroll
            for (int i = 0; i < 4; i++)
                a[i] = *(const s8v*)&At[cur][(wr * 64 + i * 16 + l16) * 64 + sw];
#pragma unroll
            for (int n = 0; n < 4; n++)
                b[n] = *(const s8v*)&Bt[cur][(wc * 64 + n * 16 + l16) * 64 + sw];
#pragma unroll
            for (int i = 0; i < 4; i++)
#pragma unroll
                for (int n = 0; n < 4; n++)
                    acc[i][n] = __builtin_amdgcn_mfma_f32_16x16x32_bf16(b[n], a[i], acc[i][n], 0, 0, 0);
        }
        if (kc < 7) __syncthreads();
        cur ^= 1;
    }
    // swapped: acc[i][n][r] -> row = mb*128+wr*64+i*16+l16, col = nb*128+wc*64+n*16+quad*4+r
#pragma unroll
    for (int i = 0; i < 4; i++)
#pragma unroll
        for (int n = 0; n < 4; n++) {
            int row = mb * 128 + wr * 64 + i * 16 + l16;
            int col = nb * 128 + wc * 64 + n * 16 + quad * 4;
            float4 o;
            o.x = acc[i][n][0]; o.y = acc[i][n][1];
            o.z = acc[i][n][2]; o.w = acc[i][n][3];
            *(float4*)&out[(size_t)row * 512 + col] = o;
        }
}

// ---------------------------------------------------------------- launch
extern "C" void kernel_launch(void* const* d_in, const int* in_sizes, int n_in,
                              void* d_out, int out_size, void* d_ws, size_t ws_size,
                              hipStream_t stream) {
    const float* x    = (const float*)d_in[0];
    const float* mask = (const float*)d_in[1];
    const float* WQ   = (const float*)d_in[2];
    const float* WK   = (const float*)d_in[3];
    const float* WV   = (const float*)d_in[4];
    const float* BE   = (const float*)d_in[5];
    const float* WO   = (const float*)d_in[6];
    float* out = (float*)d_out;

    char* ws = (char*)d_ws;
    unsigned short* hbf   = (unsigned short*)(ws);                 // 33554432 B
    unsigned short* Wqkvt = (unsigned short*)(ws + 33554432);      //  1572864 B
    unsigned short* WOt   = (unsigned short*)(ws + 35127296);      //   524288 B
    unsigned short* Qp    = (unsigned short*)(ws + 35651584);      // 33554432 B
    unsigned short* Kp    = (unsigned short*)(ws + 69206016);      // 33554432 B
    unsigned short* Vtp   = (unsigned short*)(ws + 102760448);     // 33554432 B
    unsigned short* attnp = (unsigned short*)(ws + 136314880);     // 33554432 B

    prep_h<<<16384, 256, 0, stream>>>(x, BE, hbf);
    prep_w<<<4096, 256, 0, stream>>>(WQ, WK, WV, WO, Wqkvt, WOt);
    qkv_gemm<<<dim3(12, 256), 256, 0, stream>>>(hbf, Wqkvt, Qp, Kp, Vtp);
    attn_kernel<<<dim3(2, 512), 256, 0, stream>>>(Qp, Kp, Vtp, mask, attnp);
    outproj<<<dim3(4, 256), 256, 0, stream>>>(attnp, WOt, out);
}

// Round 3
// 304.361 us; speedup vs baseline: 1.0114x; 1.0114x over previous
//
#include <hip/hip_runtime.h>
#include <hip/hip_bf16.h>

// SelfAttentionLayer: B=64 S=512 E=512 H=8 D=64
// Round 9: qkv_gemm/outproj now use COUNTED vmcnt pipeline (T4):
//   STAGE(k+1); s_waitcnt vmcnt(8); s_barrier; ds_read+MFMA(k);
//   s_waitcnt lgkmcnt(0); s_barrier.
// Next chunk's 8 global_load_lds stay in flight across the barrier —
// round-7's __syncthreads() drained vmcnt(0) and re-exposed the full
// load latency every K-step (counters: MfmaUtil flat 22%, VALU halved).
// Epilogues (packed ushort4/float4 stores via swapped mfma) kept from
// round 7. attn_kernel unchanged (verified passing).

#define Bn 64
#define Sn 512
#define En 512
#define Hn 8
#define Dn 64

typedef __attribute__((ext_vector_type(8))) short s8v;   // 8 bf16 = 4 VGPRs
typedef __attribute__((ext_vector_type(4))) float f4v;   // 4 fp32 acc

__device__ __forceinline__ unsigned short f2bf(float f) {
    union { float f; unsigned int u; } v; v.f = f;
    unsigned int u = v.u;
    u += 0x7fffu + ((u >> 16) & 1u);   // round-to-nearest-even
    return (unsigned short)(u >> 16);
}

__device__ __forceinline__ void async16(const unsigned short* g, unsigned short* l) {
    __builtin_amdgcn_global_load_lds((const __attribute__((address_space(1))) void*)g,
                                     (__attribute__((address_space(3))) void*)l, 16, 0, 0);
}
__device__ __forceinline__ void async4(const float* g, float* l) {
    __builtin_amdgcn_global_load_lds((const __attribute__((address_space(1))) void*)g,
                                     (__attribute__((address_space(3))) void*)l, 4, 0, 0);
}

// ---------------------------------------------------------------- prep_h
__global__ __launch_bounds__(256) void prep_h(const float* __restrict__ x,
                                              const float* __restrict__ BE,
                                              unsigned short* __restrict__ hbf) {
    int i = (blockIdx.x * 256 + threadIdx.x) * 4;
    int se = i % (Sn * En);
    float4 a = *(const float4*)(x + i);
    float4 b = *(const float4*)(BE + se);
    ushort4 o;
    o.x = f2bf(a.x + b.x); o.y = f2bf(a.y + b.y);
    o.z = f2bf(a.z + b.z); o.w = f2bf(a.w + b.w);
    *(ushort4*)(hbf + i) = o;
}

// ---------------------------------------------------------------- prep_w
__global__ __launch_bounds__(256) void prep_w(const float* __restrict__ WQ,
                                              const float* __restrict__ WK,
                                              const float* __restrict__ WV,
                                              const float* __restrict__ WO,
                                              unsigned short* __restrict__ Wqkvt,
                                              unsigned short* __restrict__ WOt) {
    int idx = blockIdx.x * 256 + threadIdx.x;
    const int NW = 3 * Hn * Dn * En;                   // 786432
    if (idx < NW) {
        int e = idx & 511;
        int d = (idx >> 9) & 63;
        int h = (idx >> 15) & 7;
        int m = idx >> 18;
        const float* W = (m == 0) ? WQ : (m == 1) ? WK : WV;
        Wqkvt[idx] = f2bf(W[(h * En + e) * Dn + d]);   // [m][h][d][e]
    } else {
        int j = idx - NW;
        int n = j & 511;
        int e = j >> 9;
        WOt[j] = f2bf(WO[n * En + e]);                  // WO_t[e][hd]
    }
}

// ---------------------------------------------------------------- qkv_gemm
// C[32768,1536] = hbf[32768,512] x Wqkvt^T. grid (12 nb, 256 mb), 256 thr.
// Counted-vmcnt dbuf: next chunk's loads stay in flight across barriers.
// nb<8 (Q,K): swapped mfma(B,A) -> lane holds d0..d0+3 -> ushort4 stores.
// nb>=8 (V): unswapped -> lane holds s0..s0+3 -> ushort4 stores along s.
__global__ __launch_bounds__(256) void qkv_gemm(const unsigned short* __restrict__ hbf,
                                                const unsigned short* __restrict__ Wqkvt,
                                                unsigned short* __restrict__ Qo,
                                                unsigned short* __restrict__ Ko,
                                                unsigned short* __restrict__ Vt) {
    int nb = blockIdx.x, mb = blockIdx.y;
    __shared__ __align__(16) unsigned short At[2][128 * 64];
    __shared__ __align__(16) unsigned short Bt[2][128 * 64];
    int tid = threadIdx.x;
    int w = tid >> 6, lane = tid & 63, quad = lane >> 4, l16 = lane & 15;
    int wr = w >> 1, wc = w & 1;
    int lrow = lane >> 3;
    int lseg = ((lane & 7) ^ lrow) * 8;
    bool swapQK = (nb < 8);

    f4v acc[4][4];
#pragma unroll
    for (int i = 0; i < 4; i++)
#pragma unroll
        for (int n = 0; n < 4; n++) acc[i][n] = (f4v){0.f, 0.f, 0.f, 0.f};

    const unsigned short* Ag = hbf + (size_t)mb * 128 * 512;
    const unsigned short* Bg = Wqkvt + (size_t)nb * 128 * 512;

    // prologue: stage chunk 0 into buffer 0 (8 loads/thread in flight)
#pragma unroll
    for (int i = 0; i < 4; i++) {
        int r0 = w * 32 + i * 8;
        async16(Ag + (r0 + lrow) * 512 + lseg, &At[0][r0 * 64]);
        async16(Bg + (r0 + lrow) * 512 + lseg, &Bt[0][r0 * 64]);
    }

    int cur = 0;
    for (int kc = 0; kc < 8; kc++) {
        if (kc < 7) {                              // stage next chunk into buf^1
            int nxt = cur ^ 1;
#pragma unroll
            for (int i = 0; i < 4; i++) {
                int r0 = w * 32 + i * 8;
                async16(Ag + (r0 + lrow) * 512 + (kc + 1) * 64 + lseg, &At[nxt][r0 * 64]);
                async16(Bg + (r0 + lrow) * 512 + (kc + 1) * 64 + lseg, &Bt[nxt][r0 * 64]);
            }
            // wait ONLY for chunk kc (oldest 8); chunk kc+1's 8 stay in flight
            asm volatile("s_waitcnt vmcnt(8)" ::: "memory");
        } else {
            asm volatile("s_waitcnt vmcnt(0)" ::: "memory");
        }
        __builtin_amdgcn_s_barrier();              // all waves' chunk-kc loads landed

#pragma unroll
        for (int ks = 0; ks < 2; ks++) {
            int sw = ((ks * 4 + quad) ^ (l16 & 7)) * 8;
            s8v a[4], b[4];
#pragma unroll
            for (int i = 0; i < 4; i++)
                a[i] = *(const s8v*)&At[cur][(wr * 64 + i * 16 + l16) * 64 + sw];
#pragma unroll
            for (int n = 0; n < 4; n++)
                b[n] = *(const s8v*)&Bt[cur][(wc * 64 + n * 16 + l16) * 64 + sw];
            if (swapQK) {
#pragma unroll
                for (int i = 0; i < 4; i++)
#pragma unroll
                    for (int n = 0; n < 4; n++)
                        acc[i][n] = __builtin_amdgcn_mfma_f32_16x16x32_bf16(b[n], a[i], acc[i][n], 0, 0, 0);
            } else {
#pragma unroll
                for (int i = 0; i < 4; i++)
#pragma unroll
                    for (int n = 0; n < 4; n++)
                        acc[i][n] = __builtin_amdgcn_mfma_f32_16x16x32_bf16(a[i], b[n], acc[i][n], 0, 0, 0);
            }
        }
        // reads of buf[cur] complete -> next iter may overwrite buf[cur^1]'s slot
        asm volatile("s_waitcnt lgkmcnt(0)" ::: "memory");
        __builtin_amdgcn_s_barrier();
        cur ^= 1;
    }

    int mat = nb >> 2;
    int h = (nb & 3) * 2 + wc;
    int b = mb >> 2;
    int s0 = (mb & 3) * 128 + wr * 64;
    const float qscale = 0.06375873f;   // log2(e)/sqrt(512): scale + exp->exp2 fold

    if (mat < 2) {
        // swapped layout: acc[i][n][r] -> d = n*16 + quad*4 + r, s = s0 + i*16 + l16
        unsigned short* op = (mat == 0) ? Qo : Ko;
        float sc = (mat == 0) ? qscale : 1.0f;
#pragma unroll
        for (int i = 0; i < 4; i++)
#pragma unroll
            for (int n = 0; n < 4; n++) {
                int s = s0 + i * 16 + l16;
                int d0 = n * 16 + quad * 4;
                ushort4 pk;
                pk.x = f2bf(acc[i][n][0] * sc);
                pk.y = f2bf(acc[i][n][1] * sc);
                pk.z = f2bf(acc[i][n][2] * sc);
                pk.w = f2bf(acc[i][n][3] * sc);
                *(ushort4*)&op[(size_t)((b * Hn + h) * Sn + s) * Dn + d0] = pk;
            }
    } else {
        // unswapped: V transposed Vt[b][h][d][s], packed along s
#pragma unroll
        for (int i = 0; i < 4; i++)
#pragma unroll
            for (int n = 0; n < 4; n++) {
                int d = n * 16 + l16;
                int s = s0 + i * 16 + quad * 4;
                ushort4 pk;
                pk.x = f2bf(acc[i][n][0]); pk.y = f2bf(acc[i][n][1]);
                pk.z = f2bf(acc[i][n][2]); pk.w = f2bf(acc[i][n][3]);
                *(ushort4*)&Vt[(size_t)((b * Hn + h) * Dn + d) * Sn + s] = pk;
            }
    }
}

// ---------------------------------------------------------------- attention
// grid (2 qhalf, 512 bh), 256 thr (4 waves). Wave w owns strips i=0..3
// (16 queries each of this block's 256-query half). S^T form:
//   sacc = mfma(A=K_frag, B=Q_frag): C rows = keys (key = n*16+quad*4+r),
//   col = query l16.
//   -> P packed uint2 -> b64 LDS writes, logical [query][key] swizzled
//   -> PV: A=P (b128), B=V^T rows; C rows = queries, cols = d.
__global__ __launch_bounds__(256) void attn_kernel(const unsigned short* __restrict__ Q,
                                                   const unsigned short* __restrict__ K,
                                                   const unsigned short* __restrict__ Vt,
                                                   const float* __restrict__ mask,
                                                   unsigned short* __restrict__ attn) {
    int qhalf = blockIdx.x, bh = blockIdx.y;
    int h = bh & 7, b = bh >> 3;
    __shared__ __align__(16) unsigned short Kc[64 * 64];        // [key][d] swizzled
    __shared__ __align__(16) unsigned short Vc[64 * 64];        // [d][key] swizzled
    __shared__ __align__(16) unsigned short Ps[4][4 * 16 * 64]; // [wave][strip][q][key]
    __shared__ float maskv[64];
    int tid = threadIdx.x;
    int w = tid >> 6, lane = tid & 63, quad = lane >> 4, l16 = lane & 15;
    int l7 = l16 & 7;

    const unsigned short* Qg = Q + (size_t)(bh * Sn + qhalf * 256) * Dn;
    const unsigned short* Kg = K + (size_t)(bh * Sn) * Dn;
    const unsigned short* Vg = Vt + (size_t)(bh * Dn) * Sn;

    // Q frags (A/B lane layouts identical), registers, whole kernel
    s8v aq[4][2];
#pragma unroll
    for (int i = 0; i < 4; i++)
#pragma unroll
        for (int ks = 0; ks < 2; ks++)
            aq[i][ks] = *(const s8v*)&Qg[((w * 4 + i) * 16 + l16) * 64 + ks * 32 + quad * 8];

    f4v acc[4][4];
    float psum[4] = {0.f, 0.f, 0.f, 0.f};
#pragma unroll
    for (int i = 0; i < 4; i++)
#pragma unroll
        for (int n = 0; n < 4; n++) acc[i][n] = (f4v){0.f, 0.f, 0.f, 0.f};

    // staging: each async16 covers 8 rows (64 lanes x 16B); wave w rows w*16..+15
    int srow0 = w * 16 + (lane >> 3);
    int srow1 = srow0 + 8;
    int gseg0 = ((lane & 7) ^ (srow0 & 7)) * 8;   // global seg so LDS[p] = g ^ (row&7)
    int gseg1 = ((lane & 7) ^ (srow1 & 7)) * 8;
    unsigned short* kdst0 = &Kc[(w * 16) * 64];
    unsigned short* kdst1 = &Kc[(w * 16 + 8) * 64];
    unsigned short* vdst0 = &Vc[(w * 16) * 64];
    unsigned short* vdst1 = &Vc[(w * 16 + 8) * 64];

    unsigned short* Pw = Ps[w];
    int wbase = l16 * 64 + (quad & 1) * 4;        // P write: row l16 + sub-offset
    const float cM = -1.4426950409e10f;           // -1e10 * log2(e)

    for (int kc = 0; kc < 8; kc++) {
        __syncthreads();                          // all waves done with prev chunk
        async16(Kg + (kc * 64 + srow0) * 64 + gseg0, kdst0);
        async16(Kg + (kc * 64 + srow1) * 64 + gseg1, kdst1);
        async16(Vg + srow0 * 512 + kc * 64 + gseg0, vdst0);
        async16(Vg + srow1 * 512 + kc * 64 + gseg1, vdst1);
        if (w == 0) async4(mask + b * Sn + kc * 64 + lane, maskv);
        __syncthreads();                          // vmcnt drained -> chunk ready

        // ---- S^T = K Q^T per key-tile n; bk shared across all 4 strips ----
#pragma unroll
        for (int n = 0; n < 4; n++) {
            s8v bk0 = *(const s8v*)&Kc[(n * 16 + l16) * 64 + (quad ^ l7) * 8];
            s8v bk1 = *(const s8v*)&Kc[(n * 16 + l16) * 64 + ((4 + quad) ^ l7) * 8];
            float4 mv = *(const float4*)&maskv[n * 16 + quad * 4];
            float m0 = mv.x * cM, m1 = mv.y * cM, m2 = mv.z * cM, m3 = mv.w * cM;
            int wseg = ((n * 2 + (quad >> 1)) ^ l7) * 8;
            f4v sacc[4];
#pragma unroll
            for (int i = 0; i < 4; i++) {
                sacc[i] = __builtin_amdgcn_mfma_f32_16x16x32_bf16(
                              bk0, aq[i][0], (f4v){0.f, 0.f, 0.f, 0.f}, 0, 0, 0);
                sacc[i] = __builtin_amdgcn_mfma_f32_16x16x32_bf16(
                              bk1, aq[i][1], sacc[i], 0, 0, 0);
            }
#pragma unroll
            for (int i = 0; i < 4; i++) {
                unsigned int u0 = __float_as_uint(__builtin_amdgcn_exp2f(sacc[i][0] + m0));
                unsigned int u1 = __float_as_uint(__builtin_amdgcn_exp2f(sacc[i][1] + m1));
                unsigned int u2 = __float_as_uint(__builtin_amdgcn_exp2f(sacc[i][2] + m2));
                unsigned int u3 = __float_as_uint(__builtin_amdgcn_exp2f(sacc[i][3] + m3));
                psum[i] += __uint_as_float(u0 & 0xffff0000u) + __uint_as_float(u1 & 0xffff0000u)
                         + __uint_as_float(u2 & 0xffff0000u) + __uint_as_float(u3 & 0xffff0000u);
                uint2 pk;
                pk.x = (u0 >> 16) | (u1 & 0xffff0000u);
                pk.y = (u2 >> 16) | (u3 & 0xffff0000u);
                *(uint2*)&Pw[(i << 10) + wbase + wseg] = pk;
            }
        }
        // Ps is wave-private; DS ops in-order per wave -> no barrier needed.

        // ---- O += P V : ks-outer, ap/bv shared across strips ----
#pragma unroll
        for (int ks = 0; ks < 2; ks++) {
            int sw = ((ks * 4 + quad) ^ l7) * 8;
            s8v ap[4];
#pragma unroll
            for (int i = 0; i < 4; i++)
                ap[i] = *(const s8v*)&Pw[(i << 10) + l16 * 64 + sw];
#pragma unroll
            for (int n = 0; n < 4; n++) {
                s8v bv = *(const s8v*)&Vc[(n * 16 + l16) * 64 + sw];
#pragma unroll
                for (int i = 0; i < 4; i++)
                    acc[i][n] = __builtin_amdgcn_mfma_f32_16x16x32_bf16(ap[i], bv, acc[i][n], 0, 0, 0);
            }
        }
    }

    // deferred normalization: psum[i] is quad-partial for query l16
#pragma unroll
    for (int i = 0; i < 4; i++) {
        float s = psum[i];
        s += __shfl_xor(s, 16, 64);
        s += __shfl_xor(s, 32, 64);               // every lane: total for query l16
        float inv[4];
#pragma unroll
        for (int r = 0; r < 4; r++)
            inv[r] = 1.0f / __shfl(s, quad * 4 + r, 64);
#pragma unroll
        for (int n = 0; n < 4; n++)
#pragma unroll
            for (int r = 0; r < 4; r++) {
                int query = qhalf * 256 + (w * 4 + i) * 16 + quad * 4 + r;
                int col = h * 64 + n * 16 + l16;
                attn[(size_t)(b * Sn + query) * (Hn * Dn) + col] = f2bf(acc[i][n][r] * inv[r]);
            }
    }
}

// ---------------------------------------------------------------- outproj
// out[32768,512] = attn[32768,512] x WOt^T, fp32 out. grid (4 nb, 256 mb).
// Counted-vmcnt dbuf + swapped mfma(B,A): lane holds 4 consecutive cols.
__global__ __launch_bounds__(256) void outproj(const unsigned short* __restrict__ attn,
                                               const unsigned short* __restrict__ WOt,
                                               float* __restrict__ out) {
    int nb = blockIdx.x, mb = blockIdx.y;
    __shared__ __align__(16) unsigned short At[2][128 * 64];
    __shared__ __align__(16) unsigned short Bt[2][128 * 64];
    int tid = threadIdx.x;
    int w = tid >> 6, lane = tid & 63, quad = lane >> 4, l16 = lane & 15;
    int wr = w >> 1, wc = w & 1;
    int lrow = lane >> 3;
    int lseg = ((lane & 7) ^ lrow) * 8;

    f4v acc[4][4];
#pragma unroll
    for (int i = 0; i < 4; i++)
#pragma unroll
        for (int n = 0; n < 4; n++) acc[i][n] = (f4v){0.f, 0.f, 0.f, 0.f};

    const unsigned short* Ag = attn + (size_t)mb * 128 * 512;
    const unsigned short* Bg = WOt + (size_t)nb * 128 * 512;

    // prologue: stage chunk 0
#pragma unroll
    for (int i = 0; i < 4; i++) {
        int r0 = w * 32 + i * 8;
        async16(Ag + (r0 + lrow) * 512 + lseg, &At[0][r0 * 64]);
        async16(Bg + (r0 + lrow) * 512 + lseg, &Bt[0][r0 * 64]);
    }

    int cur = 0;
    for (int kc = 0; kc < 8; kc++) {
        if (kc < 7) {
            int nxt = cur ^ 1;
#pragma unroll
            for (int i = 0; i < 4; i++) {
                int r0 = w * 32 + i * 8;
                async16(Ag + (r0 + lrow) * 512 + (kc + 1) * 64 + lseg, &At[nxt][r0 * 64]);
                async16(Bg + (r0 + lrow) * 512 + (kc + 1) * 64 + lseg, &Bt[nxt][r0 * 64]);
            }
            asm volatile("s_waitcnt vmcnt(8)" ::: "memory");
        } else {
            asm volatile("s_waitcnt vmcnt(0)" ::: "memory");
        }
        __builtin_amdgcn_s_barrier();

#pragma unroll
        for (int ks = 0; ks < 2; ks++) {
            int sw = ((ks * 4 + quad) ^ (l16 & 7)) * 8;
            s8v a[4], b[4];
#pragma unroll
            for (int i = 0; i < 4; i++)
                a[i] = *(const s8v*)&At[cur][(wr * 64 + i * 16 + l16) * 64 + sw];
#pragma unroll
            for (int n = 0; n < 4; n++)
                b[n] = *(const s8v*)&Bt[cur][(wc * 64 + n * 16 + l16) * 64 + sw];
#pragma unroll
            for (int i = 0; i < 4; i++)
#pragma unroll
                for (int n = 0; n < 4; n++)
                    acc[i][n] = __builtin_amdgcn_mfma_f32_16x16x32_bf16(b[n], a[i], acc[i][n], 0, 0, 0);
        }
        asm volatile("s_waitcnt lgkmcnt(0)" ::: "memory");
        __builtin_amdgcn_s_barrier();
        cur ^= 1;
    }
    // swapped: acc[i][n][r] -> row = mb*128+wr*64+i*16+l16, col = nb*128+wc*64+n*16+quad*4+r
#pragma unroll
    for (int i = 0; i < 4; i++)
#pragma unroll
        for (int n = 0; n < 4; n++) {
            int row = mb * 128 + wr * 64 + i * 16 + l16;
            int col = nb * 128 + wc * 64 + n * 16 + quad * 4;
            float4 o;
            o.x = acc[i][n][0]; o.y = acc[i][n][1];
            o.z = acc[i][n][2]; o.w = acc[i][n][3];
            *(float4*)&out[(size_t)row * 512 + col] = o;
        }
}

// ---------------------------------------------------------------- launch
extern "C" void kernel_launch(void* const* d_in, const int* in_sizes, int n_in,
                              void* d_out, int out_size, void* d_ws, size_t ws_size,
                              hipStream_t stream) {
    const float* x    = (const float*)d_in[0];
    const float* mask = (const float*)d_in[1];
    const float* WQ   = (const float*)d_in[2];
    const float* WK   = (const float*)d_in[3];
    const float* WV   = (const float*)d_in[4];
    const float* BE   = (const float*)d_in[5];
    const float* WO   = (const float*)d_in[6];
    float* out = (float*)d_out;

    char* ws = (char*)d_ws;
    unsigned short* hbf   = (unsigned short*)(ws);                 // 33554432 B
    unsigned short* Wqkvt = (unsigned short*)(ws + 33554432);      //  1572864 B
    unsigned short* WOt   = (unsigned short*)(ws + 35127296);      //   524288 B
    unsigned short* Qp    = (unsigned short*)(ws + 35651584);      // 33554432 B
    unsigned short* Kp    = (unsigned short*)(ws + 69206016);      // 33554432 B
    unsigned short* Vtp   = (unsigned short*)(ws + 102760448);     // 33554432 B
    unsigned short* attnp = (unsigned short*)(ws + 136314880);     // 33554432 B

    prep_h<<<16384, 256, 0, stream>>>(x, BE, hbf);
    prep_w<<<4096, 256, 0, stream>>>(WQ, WK, WV, WO, Wqkvt, WOt);
    qkv_gemm<<<dim3(12, 256), 256, 0, stream>>>(hbf, Wqkvt, Qp, Kp, Vtp);
    attn_kernel<<<dim3(2, 512), 256, 0, stream>>>(Qp, Kp, Vtp, mask, attnp);
    outproj<<<dim3(4, 256), 256, 0, stream>>>(attnp, WOt, out);
}

// Round 4
// 291.980 us; speedup vs baseline: 1.0543x; 1.0424x over previous
//
#include <hip/hip_runtime.h>
#include <hip/hip_bf16.h>

// SelfAttentionLayer: B=64 S=512 E=512 H=8 D=64
// Round 10: qkv_gemm rebuilt as the 8-phase 256^2 template (T3+T4+T5):
//   BM=BN=256, BK=64, 8 waves, 128KB LDS (2 K-tile slots, A lo/hi-interleaved
//   so phase p's a-frags = one 64-row stage unit). Per K-tile k: 4 phases
//   {ds_read; stage units of tile k+1; barrier; lgkmcnt(0); setprio(1);
//    16 MFMA; setprio(0); counted vmcnt gate; barrier}.
//   Gates vmcnt(6,6,7,2) derived from issue order — never drain to 0.
//   Bijective XCD swizzle (768%8==0): all 6 N-blocks of an A-panel on one XCD.
// Round-3 lesson: counted vmcnt on the 2-phase loop regressed (regime gate);
// 8-phase is the prerequisite. outproj/attn/preps unchanged (verified).

#define Bn 64
#define Sn 512
#define En 512
#define Hn 8
#define Dn 64

typedef __attribute__((ext_vector_type(8))) short s8v;   // 8 bf16 = 4 VGPRs
typedef __attribute__((ext_vector_type(4))) float f4v;   // 4 fp32 acc

__device__ __forceinline__ unsigned short f2bf(float f) {
    union { float f; unsigned int u; } v; v.f = f;
    unsigned int u = v.u;
    u += 0x7fffu + ((u >> 16) & 1u);   // round-to-nearest-even
    return (unsigned short)(u >> 16);
}

__device__ __forceinline__ void async16(const unsigned short* g, unsigned short* l) {
    __builtin_amdgcn_global_load_lds((const __attribute__((address_space(1))) void*)g,
                                     (__attribute__((address_space(3))) void*)l, 16, 0, 0);
}
__device__ __forceinline__ void async4(const float* g, float* l) {
    __builtin_amdgcn_global_load_lds((const __attribute__((address_space(1))) void*)g,
                                     (__attribute__((address_space(3))) void*)l, 4, 0, 0);
}

// ---------------------------------------------------------------- prep_h
__global__ __launch_bounds__(256) void prep_h(const float* __restrict__ x,
                                              const float* __restrict__ BE,
                                              unsigned short* __restrict__ hbf) {
    int i = (blockIdx.x * 256 + threadIdx.x) * 4;
    int se = i % (Sn * En);
    float4 a = *(const float4*)(x + i);
    float4 b = *(const float4*)(BE + se);
    ushort4 o;
    o.x = f2bf(a.x + b.x); o.y = f2bf(a.y + b.y);
    o.z = f2bf(a.z + b.z); o.w = f2bf(a.w + b.w);
    *(ushort4*)(hbf + i) = o;
}

// ---------------------------------------------------------------- prep_w
__global__ __launch_bounds__(256) void prep_w(const float* __restrict__ WQ,
                                              const float* __restrict__ WK,
                                              const float* __restrict__ WV,
                                              const float* __restrict__ WO,
                                              unsigned short* __restrict__ Wqkvt,
                                              unsigned short* __restrict__ WOt) {
    int idx = blockIdx.x * 256 + threadIdx.x;
    const int NW = 3 * Hn * Dn * En;                   // 786432
    if (idx < NW) {
        int e = idx & 511;
        int d = (idx >> 9) & 63;
        int h = (idx >> 15) & 7;
        int m = idx >> 18;
        const float* W = (m == 0) ? WQ : (m == 1) ? WK : WV;
        Wqkvt[idx] = f2bf(W[(h * En + e) * Dn + d]);   // [m][h][d][e]
    } else {
        int j = idx - NW;
        int n = j & 511;
        int e = j >> 9;
        WOt[j] = f2bf(WO[n * En + e]);                  // WO_t[e][hd]
    }
}

// ---------------------------------------------------------------- qkv_gemm
// C[32768,1536] = hbf[32768,512] x Wqkvt^T. 8-phase 256^2 schedule.
// grid (6 nbv, 128 mb), 512 thr (8 waves, 2M x 4N). Wave tile 128x64.
// LDS: As/Bs[2][256*64] bf16 (A rows lo/hi interleaved: lr=2*(gr&127)+(gr>>7)).
// Q/K waves (colbase<1024): swapped mfma(B,A) -> packed ushort4 along d.
// V waves: unswapped -> packed ushort4 along s into Vt[b][h][d][s].
__device__ __forceinline__ void mfma8(const s8v& a0k0, const s8v& a0k1,
                                      const s8v& a1k0, const s8v& a1k1,
                                      f4v* acc0, f4v* acc1,
                                      const s8v (&bq)[4][2], bool sw) {
    if (sw) {
#pragma unroll
        for (int n = 0; n < 4; n++) {
            acc0[n] = __builtin_amdgcn_mfma_f32_16x16x32_bf16(bq[n][0], a0k0, acc0[n], 0, 0, 0);
            acc0[n] = __builtin_amdgcn_mfma_f32_16x16x32_bf16(bq[n][1], a0k1, acc0[n], 0, 0, 0);
            acc1[n] = __builtin_amdgcn_mfma_f32_16x16x32_bf16(bq[n][0], a1k0, acc1[n], 0, 0, 0);
            acc1[n] = __builtin_amdgcn_mfma_f32_16x16x32_bf16(bq[n][1], a1k1, acc1[n], 0, 0, 0);
        }
    } else {
#pragma unroll
        for (int n = 0; n < 4; n++) {
            acc0[n] = __builtin_amdgcn_mfma_f32_16x16x32_bf16(a0k0, bq[n][0], acc0[n], 0, 0, 0);
            acc0[n] = __builtin_amdgcn_mfma_f32_16x16x32_bf16(a0k1, bq[n][1], acc0[n], 0, 0, 0);
            acc1[n] = __builtin_amdgcn_mfma_f32_16x16x32_bf16(a1k0, bq[n][0], acc1[n], 0, 0, 0);
            acc1[n] = __builtin_amdgcn_mfma_f32_16x16x32_bf16(a1k1, bq[n][1], acc1[n], 0, 0, 0);
        }
    }
}

__global__ __launch_bounds__(512, 2) void qkv_gemm(const unsigned short* __restrict__ hbf,
                                                   const unsigned short* __restrict__ Wqkvt,
                                                   unsigned short* __restrict__ Qo,
                                                   unsigned short* __restrict__ Ko,
                                                   unsigned short* __restrict__ Vt) {
    __shared__ __align__(16) unsigned short As[2][16384];   // 64KB
    __shared__ __align__(16) unsigned short Bs[2][16384];   // 64KB

    int lin = blockIdx.y * 6 + blockIdx.x;                  // 768 blocks
    int swz = (lin & 7) * 96 + (lin >> 3);                  // bijective XCD swizzle
    int mb = swz / 6, nbv = swz - mb * 6;

    int tid = threadIdx.x;
    int w = tid >> 6, lane = tid & 63, quad = lane >> 4, l16 = lane & 15, l7 = l16 & 7;
    int wr = w >> 2, wcn = w & 3;

    const unsigned short* Ag = hbf + (size_t)mb * 256 * 512;
    const unsigned short* Bg = Wqkvt + (size_t)nbv * 256 * 512;

    int colbase = nbv * 256 + wcn * 64;
    bool swapQK = colbase < 1024;

    // staging address constants (pre-swizzled global source, linear LDS dst)
    int ha = (lane >> 3) & 1;                               // A hi/lo half
    int ca = w * 4 + (lane >> 4);                           // A m-part 0..31
    int aG0 = (ca + 128 * ha) * 512 + ((lane & 7) ^ (ca & 7)) * 8;
    int rb0 = w * 8 + (lane >> 3);                          // B row 0..63
    int bG0 = rb0 * 512 + ((lane & 7) ^ (rb0 & 7)) * 8;

    // ds_read constants
    int arow = 2 * l16 + wr;                                // A interleaved row term
    int aseg0 = (quad ^ l7) * 8;                            // ks=0 swizzled seg
    int aseg1 = ((4 + quad) ^ l7) * 8;                      // ks=1

    f4v acc[8][4];
#pragma unroll
    for (int i = 0; i < 8; i++)
#pragma unroll
        for (int n = 0; n < 4; n++) acc[i][n] = (f4v){0.f, 0.f, 0.f, 0.f};
    s8v bq[4][2];

// stage unit macros: one block-wide 64-row op each (1 intrinsic/thread)
#define STA8(o_, p_, kt_) async16(Ag + aG0 + (p_) * 16384 + (kt_) * 64, &As[o_][(p_) * 4096 + w * 512])
#define STB8(o_, q_, kt_) async16(Bg + bG0 + (q_) * 32768 + (kt_) * 64, &Bs[o_][(q_) * 4096 + w * 512])

#define PHASE8(P, STAGES, GATE)                                                   \
    do {                                                                          \
        if ((P) == 0) {                                                           \
            _Pragma("unroll")                                                     \
            for (int n = 0; n < 4; n++) {                                         \
                int br = (wcn * 64 + n * 16 + l16) * 64;                          \
                bq[n][0] = *(const s8v*)&Bs_s[br + aseg0];                        \
                bq[n][1] = *(const s8v*)&Bs_s[br + aseg1];                        \
            }                                                                     \
        }                                                                         \
        s8v a0k0 = *(const s8v*)&As_s[(((P) * 2 + 0) * 32 + arow) * 64 + aseg0];  \
        s8v a0k1 = *(const s8v*)&As_s[(((P) * 2 + 0) * 32 + arow) * 64 + aseg1];  \
        s8v a1k0 = *(const s8v*)&As_s[(((P) * 2 + 1) * 32 + arow) * 64 + aseg0];  \
        s8v a1k1 = *(const s8v*)&As_s[(((P) * 2 + 1) * 32 + arow) * 64 + aseg1];  \
        STAGES;                                                                   \
        __builtin_amdgcn_s_barrier();                                             \
        asm volatile("s_waitcnt lgkmcnt(0)" ::: "memory");                        \
        __builtin_amdgcn_s_setprio(1);                                            \
        mfma8(a0k0, a0k1, a1k0, a1k1, &acc[(P) * 2][0], &acc[(P) * 2 + 1][0], bq, swapQK); \
        __builtin_amdgcn_s_setprio(0);                                            \
        GATE;                                                                     \
        __builtin_amdgcn_s_barrier();                                             \
    } while (0)

    // prologue: K-tile 0 fully staged into slot 0, drained once
    STB8(0, 0, 0); STB8(0, 1, 0); STB8(0, 2, 0); STB8(0, 3, 0);
    STA8(0, 0, 0); STA8(0, 1, 0); STA8(0, 2, 0); STA8(0, 3, 0);
    asm volatile("s_waitcnt vmcnt(0)" ::: "memory");
    __builtin_amdgcn_s_barrier();

    for (int k = 0; k < 7; k++) {
        int s = k & 1, o = s ^ 1, kt = k + 1;
        const unsigned short* As_s = &As[s][0];
        const unsigned short* Bs_s = &Bs[s][0];
        PHASE8(0, { STB8(o, 0, kt); STB8(o, 1, kt); STA8(o, 0, kt); },
               asm volatile("s_waitcnt vmcnt(6)" ::: "memory"));
        PHASE8(1, { STB8(o, 2, kt); STA8(o, 1, kt); },
               asm volatile("s_waitcnt vmcnt(6)" ::: "memory"));
        PHASE8(2, { STB8(o, 3, kt); STA8(o, 2, kt); },
               asm volatile("s_waitcnt vmcnt(7)" ::: "memory"));
        PHASE8(3, { STA8(o, 3, kt); },
               asm volatile("s_waitcnt vmcnt(2)" ::: "memory"));
    }
    {   // tail K-tile 7 (slot 1): no staging, gradual drain
        const unsigned short* As_s = &As[1][0];
        const unsigned short* Bs_s = &Bs[1][0];
        PHASE8(0, {}, asm volatile("s_waitcnt vmcnt(3)" ::: "memory"));
        PHASE8(1, {}, asm volatile("s_waitcnt vmcnt(1)" ::: "memory"));
        PHASE8(2, {}, asm volatile("s_waitcnt vmcnt(0)" ::: "memory"));
        PHASE8(3, {}, (void)0);
    }
#undef PHASE8
#undef STA8
#undef STB8

    int mat = colbase >> 9;
    int h = (colbase >> 6) & 7;
    int b_idx = mb >> 1;
    const float qscale = 0.06375873f;   // log2(e)/sqrt(512): scale + exp->exp2 fold

    if (swapQK) {
        // swapped: acc[mi][n][r] -> d = n*16+quad*4+r, s = (mb&1)*256+wr*128+mi*16+l16
        unsigned short* op = (mat == 0) ? Qo : Ko;
        float sc = (mat == 0) ? qscale : 1.0f;
#pragma unroll
        for (int mi = 0; mi < 8; mi++)
#pragma unroll
            for (int n = 0; n < 4; n++) {
                int s_ = (mb & 1) * 256 + wr * 128 + mi * 16 + l16;
                int d0 = n * 16 + quad * 4;
                ushort4 pk;
                pk.x = f2bf(acc[mi][n][0] * sc);
                pk.y = f2bf(acc[mi][n][1] * sc);
                pk.z = f2bf(acc[mi][n][2] * sc);
                pk.w = f2bf(acc[mi][n][3] * sc);
                *(ushort4*)&op[(size_t)((b_idx * Hn + h) * Sn + s_) * Dn + d0] = pk;
            }
    } else {
        // unswapped: V transposed Vt[b][h][d][s], packed along s
#pragma unroll
        for (int mi = 0; mi < 8; mi++)
#pragma unroll
            for (int n = 0; n < 4; n++) {
                int d = n * 16 + l16;
                int srow = (mb & 1) * 256 + wr * 128 + mi * 16 + quad * 4;
                ushort4 pk;
                pk.x = f2bf(acc[mi][n][0]); pk.y = f2bf(acc[mi][n][1]);
                pk.z = f2bf(acc[mi][n][2]); pk.w = f2bf(acc[mi][n][3]);
                *(ushort4*)&Vt[(size_t)((b_idx * Hn + h) * Dn + d) * Sn + srow] = pk;
            }
    }
}

// ---------------------------------------------------------------- attention
// grid (2 qhalf, 512 bh), 256 thr (4 waves). Wave w owns strips i=0..3
// (16 queries each of this block's 256-query half). S^T form:
//   sacc = mfma(A=K_frag, B=Q_frag): C rows = keys (key = n*16+quad*4+r),
//   col = query l16.
//   -> P packed uint2 -> b64 LDS writes, logical [query][key] swizzled
//   -> PV: A=P (b128), B=V^T rows; C rows = queries, cols = d.
__global__ __launch_bounds__(256) void attn_kernel(const unsigned short* __restrict__ Q,
                                                   const unsigned short* __restrict__ K,
                                                   const unsigned short* __restrict__ Vt,
                                                   const float* __restrict__ mask,
                                                   unsigned short* __restrict__ attn) {
    int qhalf = blockIdx.x, bh = blockIdx.y;
    int h = bh & 7, b = bh >> 3;
    __shared__ __align__(16) unsigned short Kc[64 * 64];        // [key][d] swizzled
    __shared__ __align__(16) unsigned short Vc[64 * 64];        // [d][key] swizzled
    __shared__ __align__(16) unsigned short Ps[4][4 * 16 * 64]; // [wave][strip][q][key]
    __shared__ float maskv[64];
    int tid = threadIdx.x;
    int w = tid >> 6, lane = tid & 63, quad = lane >> 4, l16 = lane & 15;
    int l7 = l16 & 7;

    const unsigned short* Qg = Q + (size_t)(bh * Sn + qhalf * 256) * Dn;
    const unsigned short* Kg = K + (size_t)(bh * Sn) * Dn;
    const unsigned short* Vg = Vt + (size_t)(bh * Dn) * Sn;

    // Q frags (A/B lane layouts identical), registers, whole kernel
    s8v aq[4][2];
#pragma unroll
    for (int i = 0; i < 4; i++)
#pragma unroll
        for (int ks = 0; ks < 2; ks++)
            aq[i][ks] = *(const s8v*)&Qg[((w * 4 + i) * 16 + l16) * 64 + ks * 32 + quad * 8];

    f4v acc[4][4];
    float psum[4] = {0.f, 0.f, 0.f, 0.f};
#pragma unroll
    for (int i = 0; i < 4; i++)
#pragma unroll
        for (int n = 0; n < 4; n++) acc[i][n] = (f4v){0.f, 0.f, 0.f, 0.f};

    // staging: each async16 covers 8 rows (64 lanes x 16B); wave w rows w*16..+15
    int srow0 = w * 16 + (lane >> 3);
    int srow1 = srow0 + 8;
    int gseg0 = ((lane & 7) ^ (srow0 & 7)) * 8;   // global seg so LDS[p] = g ^ (row&7)
    int gseg1 = ((lane & 7) ^ (srow1 & 7)) * 8;
    unsigned short* kdst0 = &Kc[(w * 16) * 64];
    unsigned short* kdst1 = &Kc[(w * 16 + 8) * 64];
    unsigned short* vdst0 = &Vc[(w * 16) * 64];
    unsigned short* vdst1 = &Vc[(w * 16 + 8) * 64];

    unsigned short* Pw = Ps[w];
    int wbase = l16 * 64 + (quad & 1) * 4;        // P write: row l16 + sub-offset
    const float cM = -1.4426950409e10f;           // -1e10 * log2(e)

    for (int kc = 0; kc < 8; kc++) {
        __syncthreads();                          // all waves done with prev chunk
        async16(Kg + (kc * 64 + srow0) * 64 + gseg0, kdst0);
        async16(Kg + (kc * 64 + srow1) * 64 + gseg1, kdst1);
        async16(Vg + srow0 * 512 + kc * 64 + gseg0, vdst0);
        async16(Vg + srow1 * 512 + kc * 64 + gseg1, vdst1);
        if (w == 0) async4(mask + b * Sn + kc * 64 + lane, maskv);
        __syncthreads();                          // vmcnt drained -> chunk ready

        // ---- S^T = K Q^T per key-tile n; bk shared across all 4 strips ----
#pragma unroll
        for (int n = 0; n < 4; n++) {
            s8v bk0 = *(const s8v*)&Kc[(n * 16 + l16) * 64 + (quad ^ l7) * 8];
            s8v bk1 = *(const s8v*)&Kc[(n * 16 + l16) * 64 + ((4 + quad) ^ l7) * 8];
            float4 mv = *(const float4*)&maskv[n * 16 + quad * 4];
            float m0 = mv.x * cM, m1 = mv.y * cM, m2 = mv.z * cM, m3 = mv.w * cM;
            int wseg = ((n * 2 + (quad >> 1)) ^ l7) * 8;
            f4v sacc[4];
#pragma unroll
            for (int i = 0; i < 4; i++) {
                sacc[i] = __builtin_amdgcn_mfma_f32_16x16x32_bf16(
                              bk0, aq[i][0], (f4v){0.f, 0.f, 0.f, 0.f}, 0, 0, 0);
                sacc[i] = __builtin_amdgcn_mfma_f32_16x16x32_bf16(
                              bk1, aq[i][1], sacc[i], 0, 0, 0);
            }
#pragma unroll
            for (int i = 0; i < 4; i++) {
                unsigned int u0 = __float_as_uint(__builtin_amdgcn_exp2f(sacc[i][0] + m0));
                unsigned int u1 = __float_as_uint(__builtin_amdgcn_exp2f(sacc[i][1] + m1));
                unsigned int u2 = __float_as_uint(__builtin_amdgcn_exp2f(sacc[i][2] + m2));
                unsigned int u3 = __float_as_uint(__builtin_amdgcn_exp2f(sacc[i][3] + m3));
                psum[i] += __uint_as_float(u0 & 0xffff0000u) + __uint_as_float(u1 & 0xffff0000u)
                         + __uint_as_float(u2 & 0xffff0000u) + __uint_as_float(u3 & 0xffff0000u);
                uint2 pk;
                pk.x = (u0 >> 16) | (u1 & 0xffff0000u);
                pk.y = (u2 >> 16) | (u3 & 0xffff0000u);
                *(uint2*)&Pw[(i << 10) + wbase + wseg] = pk;
            }
        }
        // Ps is wave-private; DS ops in-order per wave -> no barrier needed.

        // ---- O += P V : ks-outer, ap/bv shared across strips ----
#pragma unroll
        for (int ks = 0; ks < 2; ks++) {
            int sw = ((ks * 4 + quad) ^ l7) * 8;
            s8v ap[4];
#pragma unroll
            for (int i = 0; i < 4; i++)
                ap[i] = *(const s8v*)&Pw[(i << 10) + l16 * 64 + sw];
#pragma unroll
            for (int n = 0; n < 4; n++) {
                s8v bv = *(const s8v*)&Vc[(n * 16 + l16) * 64 + sw];
#pragma unroll
                for (int i = 0; i < 4; i++)
                    acc[i][n] = __builtin_amdgcn_mfma_f32_16x16x32_bf16(ap[i], bv, acc[i][n], 0, 0, 0);
            }
        }
    }

    // deferred normalization: psum[i] is quad-partial for query l16
#pragma unroll
    for (int i = 0; i < 4; i++) {
        float s = psum[i];
        s += __shfl_xor(s, 16, 64);
        s += __shfl_xor(s, 32, 64);               // every lane: total for query l16
        float inv[4];
#pragma unroll
        for (int r = 0; r < 4; r++)
            inv[r] = 1.0f / __shfl(s, quad * 4 + r, 64);
#pragma unroll
        for (int n = 0; n < 4; n++)
#pragma unroll
            for (int r = 0; r < 4; r++) {
                int query = qhalf * 256 + (w * 4 + i) * 16 + quad * 4 + r;
                int col = h * 64 + n * 16 + l16;
                attn[(size_t)(b * Sn + query) * (Hn * Dn) + col] = f2bf(acc[i][n][r] * inv[r]);
            }
    }
}

// ---------------------------------------------------------------- outproj
// out[32768,512] = attn[32768,512] x WOt^T, fp32 out. grid (4 nb, 256 mb).
// Counted-vmcnt dbuf + swapped mfma(B,A): lane holds 4 consecutive cols.
__global__ __launch_bounds__(256) void outproj(const unsigned short* __restrict__ attn,
                                               const unsigned short* __restrict__ WOt,
                                               float* __restrict__ out) {
    int nb = blockIdx.x, mb = blockIdx.y;
    __shared__ __align__(16) unsigned short At[2][128 * 64];
    __shared__ __align__(16) unsigned short Bt[2][128 * 64];
    int tid = threadIdx.x;
    int w = tid >> 6, lane = tid & 63, quad = lane >> 4, l16 = lane & 15;
    int wr = w >> 1, wc = w & 1;
    int lrow = lane >> 3;
    int lseg = ((lane & 7) ^ lrow) * 8;

    f4v acc[4][4];
#pragma unroll
    for (int i = 0; i < 4; i++)
#pragma unroll
        for (int n = 0; n < 4; n++) acc[i][n] = (f4v){0.f, 0.f, 0.f, 0.f};

    const unsigned short* Ag = attn + (size_t)mb * 128 * 512;
    const unsigned short* Bg = WOt + (size_t)nb * 128 * 512;

    // prologue: stage chunk 0
#pragma unroll
    for (int i = 0; i < 4; i++) {
        int r0 = w * 32 + i * 8;
        async16(Ag + (r0 + lrow) * 512 + lseg, &At[0][r0 * 64]);
        async16(Bg + (r0 + lrow) * 512 + lseg, &Bt[0][r0 * 64]);
    }

    int cur = 0;
    for (int kc = 0; kc < 8; kc++) {
        if (kc < 7) {
            int nxt = cur ^ 1;
#pragma unroll
            for (int i = 0; i < 4; i++) {
                int r0 = w * 32 + i * 8;
                async16(Ag + (r0 + lrow) * 512 + (kc + 1) * 64 + lseg, &At[nxt][r0 * 64]);
                async16(Bg + (r0 + lrow) * 512 + (kc + 1) * 64 + lseg, &Bt[nxt][r0 * 64]);
            }
            asm volatile("s_waitcnt vmcnt(8)" ::: "memory");
        } else {
            asm volatile("s_waitcnt vmcnt(0)" ::: "memory");
        }
        __builtin_amdgcn_s_barrier();

#pragma unroll
        for (int ks = 0; ks < 2; ks++) {
            int sw = ((ks * 4 + quad) ^ (l16 & 7)) * 8;
            s8v a[4], b[4];
#pragma unroll
            for (int i = 0; i < 4; i++)
                a[i] = *(const s8v*)&At[cur][(wr * 64 + i * 16 + l16) * 64 + sw];
#pragma unroll
            for (int n = 0; n < 4; n++)
                b[n] = *(const s8v*)&Bt[cur][(wc * 64 + n * 16 + l16) * 64 + sw];
#pragma unroll
            for (int i = 0; i < 4; i++)
#pragma unroll
                for (int n = 0; n < 4; n++)
                    acc[i][n] = __builtin_amdgcn_mfma_f32_16x16x32_bf16(b[n], a[i], acc[i][n], 0, 0, 0);
        }
        asm volatile("s_waitcnt lgkmcnt(0)" ::: "memory");
        __builtin_amdgcn_s_barrier();
        cur ^= 1;
    }
    // swapped: acc[i][n][r] -> row = mb*128+wr*64+i*16+l16, col = nb*128+wc*64+n*16+quad*4+r
#pragma unroll
    for (int i = 0; i < 4; i++)
#pragma unroll
        for (int n = 0; n < 4; n++) {
            int row = mb * 128 + wr * 64 + i * 16 + l16;
            int col = nb * 128 + wc * 64 + n * 16 + quad * 4;
            float4 o;
            o.x = acc[i][n][0]; o.y = acc[i][n][1];
            o.z = acc[i][n][2]; o.w = acc[i][n][3];
            *(float4*)&out[(size_t)row * 512 + col] = o;
        }
}

// ---------------------------------------------------------------- launch
extern "C" void kernel_launch(void* const* d_in, const int* in_sizes, int n_in,
                              void* d_out, int out_size, void* d_ws, size_t ws_size,
                              hipStream_t stream) {
    const float* x    = (const float*)d_in[0];
    const float* mask = (const float*)d_in[1];
    const float* WQ   = (const float*)d_in[2];
    const float* WK   = (const float*)d_in[3];
    const float* WV   = (const float*)d_in[4];
    const float* BE   = (const float*)d_in[5];
    const float* WO   = (const float*)d_in[6];
    float* out = (float*)d_out;

    char* ws = (char*)d_ws;
    unsigned short* hbf   = (unsigned short*)(ws);                 // 33554432 B
    unsigned short* Wqkvt = (unsigned short*)(ws + 33554432);      //  1572864 B
    unsigned short* WOt   = (unsigned short*)(ws + 35127296);      //   524288 B
    unsigned short* Qp    = (unsigned short*)(ws + 35651584);      // 33554432 B
    unsigned short* Kp    = (unsigned short*)(ws + 69206016);      // 33554432 B
    unsigned short* Vtp   = (unsigned short*)(ws + 102760448);     // 33554432 B
    unsigned short* attnp = (unsigned short*)(ws + 136314880);     // 33554432 B

    prep_h<<<16384, 256, 0, stream>>>(x, BE, hbf);
    prep_w<<<4096, 256, 0, stream>>>(WQ, WK, WV, WO, Wqkvt, WOt);
    qkv_gemm<<<dim3(6, 128), 512, 0, stream>>>(hbf, Wqkvt, Qp, Kp, Vtp);
    attn_kernel<<<dim3(2, 512), 256, 0, stream>>>(Qp, Kp, Vtp, mask, attnp);
    outproj<<<dim3(4, 256), 256, 0, stream>>>(attnp, WOt, out);
}

// Round 5
// 291.364 us; speedup vs baseline: 1.0565x; 1.0021x over previous
//
#include <hip/hip_runtime.h>
#include <hip/hip_bf16.h>

// SelfAttentionLayer: B=64 S=512 E=512 H=8 D=64
// Round 11: qkv_gemm gate restructure (issue-early / gate-late).
// Round-10's staging {3,2,2,1}/gates(6,6,7,2) forced ph3 to wait on a
// unit issued ONE phase earlier (~150cy cover vs ~900cy HBM) -> per-tile
// stall. New: stage {ph0: B0..B3,A0 | ph1: A1,A2,A3}, gates
// ph0 vmcnt(7), ph1 vmcnt(8), ph2 none, ph3 vmcnt(3) — every gated load
// has >=3 phases of MFMA cover. Queue proof in comments. Everything else
// (XCD swizzle — FETCH 139->37MB confirmed — epilogues, attn, outproj,
// preps) unchanged from round 10 (verified passing).

#define Bn 64
#define Sn 512
#define En 512
#define Hn 8
#define Dn 64

typedef __attribute__((ext_vector_type(8))) short s8v;   // 8 bf16 = 4 VGPRs
typedef __attribute__((ext_vector_type(4))) float f4v;   // 4 fp32 acc

__device__ __forceinline__ unsigned short f2bf(float f) {
    union { float f; unsigned int u; } v; v.f = f;
    unsigned int u = v.u;
    u += 0x7fffu + ((u >> 16) & 1u);   // round-to-nearest-even
    return (unsigned short)(u >> 16);
}

__device__ __forceinline__ void async16(const unsigned short* g, unsigned short* l) {
    __builtin_amdgcn_global_load_lds((const __attribute__((address_space(1))) void*)g,
                                     (__attribute__((address_space(3))) void*)l, 16, 0, 0);
}
__device__ __forceinline__ void async4(const float* g, float* l) {
    __builtin_amdgcn_global_load_lds((const __attribute__((address_space(1))) void*)g,
                                     (__attribute__((address_space(3))) void*)l, 4, 0, 0);
}

// ---------------------------------------------------------------- prep_h
__global__ __launch_bounds__(256) void prep_h(const float* __restrict__ x,
                                              const float* __restrict__ BE,
                                              unsigned short* __restrict__ hbf) {
    int i = (blockIdx.x * 256 + threadIdx.x) * 4;
    int se = i % (Sn * En);
    float4 a = *(const float4*)(x + i);
    float4 b = *(const float4*)(BE + se);
    ushort4 o;
    o.x = f2bf(a.x + b.x); o.y = f2bf(a.y + b.y);
    o.z = f2bf(a.z + b.z); o.w = f2bf(a.w + b.w);
    *(ushort4*)(hbf + i) = o;
}

// ---------------------------------------------------------------- prep_w
__global__ __launch_bounds__(256) void prep_w(const float* __restrict__ WQ,
                                              const float* __restrict__ WK,
                                              const float* __restrict__ WV,
                                              const float* __restrict__ WO,
                                              unsigned short* __restrict__ Wqkvt,
                                              unsigned short* __restrict__ WOt) {
    int idx = blockIdx.x * 256 + threadIdx.x;
    const int NW = 3 * Hn * Dn * En;                   // 786432
    if (idx < NW) {
        int e = idx & 511;
        int d = (idx >> 9) & 63;
        int h = (idx >> 15) & 7;
        int m = idx >> 18;
        const float* W = (m == 0) ? WQ : (m == 1) ? WK : WV;
        Wqkvt[idx] = f2bf(W[(h * En + e) * Dn + d]);   // [m][h][d][e]
    } else {
        int j = idx - NW;
        int n = j & 511;
        int e = j >> 9;
        WOt[j] = f2bf(WO[n * En + e]);                  // WO_t[e][hd]
    }
}

// ---------------------------------------------------------------- qkv_gemm
// C[32768,1536] = hbf[32768,512] x Wqkvt^T. 8-phase 256^2 schedule.
// grid (6 nbv, 128 mb), 512 thr (8 waves, 2M x 4N). Wave tile 128x64.
// LDS: As/Bs[2][256*64] bf16 (A rows lo/hi interleaved: lr=2*(gr&127)+(gr>>7)).
// Phase p reads A unit p (LDS rows p*64..p*64+63) + (ph0 only) B units.
// Steady-state queue (oldest first), entering tile k = [kA1,kA2,kA3]:
//   ph0: reads kB*,kA0 (landed via k-1 ph3 gate); stage B0'..B3',A0' -> 8;
//        gate vmcnt(7) retires kA1 (issued k-1 ph1: 3 phases cover)
//   ph1: reads kA1; stage A1',A2',A3' -> 10; gate vmcnt(8) retires kA2,kA3
//   ph2: reads kA2 (landed); no stage; no gate
//   ph3: reads kA3 (landed); gate vmcnt(3) retires B0'..B3',A0'
//        (issued ph0: 3 phases cover) -> leaves [A1',A2',A3'] = invariant.
__device__ __forceinline__ void mfma8(const s8v& a0k0, const s8v& a0k1,
                                      const s8v& a1k0, const s8v& a1k1,
                                      f4v* acc0, f4v* acc1,
                                      const s8v (&bq)[4][2], bool sw) {
    if (sw) {
#pragma unroll
        for (int n = 0; n < 4; n++) {
            acc0[n] = __builtin_amdgcn_mfma_f32_16x16x32_bf16(bq[n][0], a0k0, acc0[n], 0, 0, 0);
            acc0[n] = __builtin_amdgcn_mfma_f32_16x16x32_bf16(bq[n][1], a0k1, acc0[n], 0, 0, 0);
            acc1[n] = __builtin_amdgcn_mfma_f32_16x16x32_bf16(bq[n][0], a1k0, acc1[n], 0, 0, 0);
            acc1[n] = __builtin_amdgcn_mfma_f32_16x16x32_bf16(bq[n][1], a1k1, acc1[n], 0, 0, 0);
        }
    } else {
#pragma unroll
        for (int n = 0; n < 4; n++) {
            acc0[n] = __builtin_amdgcn_mfma_f32_16x16x32_bf16(a0k0, bq[n][0], acc0[n], 0, 0, 0);
            acc0[n] = __builtin_amdgcn_mfma_f32_16x16x32_bf16(a0k1, bq[n][1], acc0[n], 0, 0, 0);
            acc1[n] = __builtin_amdgcn_mfma_f32_16x16x32_bf16(a1k0, bq[n][0], acc1[n], 0, 0, 0);
            acc1[n] = __builtin_amdgcn_mfma_f32_16x16x32_bf16(a1k1, bq[n][1], acc1[n], 0, 0, 0);
        }
    }
}

__global__ __launch_bounds__(512, 2) void qkv_gemm(const unsigned short* __restrict__ hbf,
                                                   const unsigned short* __restrict__ Wqkvt,
                                                   unsigned short* __restrict__ Qo,
                                                   unsigned short* __restrict__ Ko,
                                                   unsigned short* __restrict__ Vt) {
    __shared__ __align__(16) unsigned short As[2][16384];   // 64KB
    __shared__ __align__(16) unsigned short Bs[2][16384];   // 64KB

    int lin = blockIdx.y * 6 + blockIdx.x;                  // 768 blocks
    int swz = (lin & 7) * 96 + (lin >> 3);                  // bijective XCD swizzle
    int mb = swz / 6, nbv = swz - mb * 6;

    int tid = threadIdx.x;
    int w = tid >> 6, lane = tid & 63, quad = lane >> 4, l16 = lane & 15, l7 = l16 & 7;
    int wr = w >> 2, wcn = w & 3;

    const unsigned short* Ag = hbf + (size_t)mb * 256 * 512;
    const unsigned short* Bg = Wqkvt + (size_t)nbv * 256 * 512;

    int colbase = nbv * 256 + wcn * 64;
    bool swapQK = colbase < 1024;

    // staging address constants (pre-swizzled global source, linear LDS dst)
    int ha = (lane >> 3) & 1;                               // A hi/lo half
    int ca = w * 4 + (lane >> 4);                           // A m-part 0..31
    int aG0 = (ca + 128 * ha) * 512 + ((lane & 7) ^ (ca & 7)) * 8;
    int rb0 = w * 8 + (lane >> 3);                          // B row 0..63
    int bG0 = rb0 * 512 + ((lane & 7) ^ (rb0 & 7)) * 8;

    // ds_read constants
    int arow = 2 * l16 + wr;                                // A interleaved row term
    int aseg0 = (quad ^ l7) * 8;                            // ks=0 swizzled seg
    int aseg1 = ((4 + quad) ^ l7) * 8;                      // ks=1

    f4v acc[8][4];
#pragma unroll
    for (int i = 0; i < 8; i++)
#pragma unroll
        for (int n = 0; n < 4; n++) acc[i][n] = (f4v){0.f, 0.f, 0.f, 0.f};
    s8v bq[4][2];

// stage unit macros: one block-wide 64-row op each (1 intrinsic/thread)
#define STA8(o_, p_, kt_) async16(Ag + aG0 + (p_) * 16384 + (kt_) * 64, &As[o_][(p_) * 4096 + w * 512])
#define STB8(o_, q_, kt_) async16(Bg + bG0 + (q_) * 32768 + (kt_) * 64, &Bs[o_][(q_) * 4096 + w * 512])

#define PHASE8(P, STAGES, GATE)                                                   \
    do {                                                                          \
        if ((P) == 0) {                                                           \
            _Pragma("unroll")                                                     \
            for (int n = 0; n < 4; n++) {                                         \
                int br = (wcn * 64 + n * 16 + l16) * 64;                          \
                bq[n][0] = *(const s8v*)&Bs_s[br + aseg0];                        \
                bq[n][1] = *(const s8v*)&Bs_s[br + aseg1];                        \
            }                                                                     \
        }                                                                         \
        s8v a0k0 = *(const s8v*)&As_s[(((P) * 2 + 0) * 32 + arow) * 64 + aseg0];  \
        s8v a0k1 = *(const s8v*)&As_s[(((P) * 2 + 0) * 32 + arow) * 64 + aseg1];  \
        s8v a1k0 = *(const s8v*)&As_s[(((P) * 2 + 1) * 32 + arow) * 64 + aseg0];  \
        s8v a1k1 = *(const s8v*)&As_s[(((P) * 2 + 1) * 32 + arow) * 64 + aseg1];  \
        STAGES;                                                                   \
        __builtin_amdgcn_s_barrier();                                             \
        asm volatile("s_waitcnt lgkmcnt(0)" ::: "memory");                        \
        __builtin_amdgcn_s_setprio(1);                                            \
        mfma8(a0k0, a0k1, a1k0, a1k1, &acc[(P) * 2][0], &acc[(P) * 2 + 1][0], bq, swapQK); \
        __builtin_amdgcn_s_setprio(0);                                            \
        GATE;                                                                     \
        __builtin_amdgcn_s_barrier();                                             \
    } while (0)

    // prologue: tile 0 staged in steady-state order; gate matches invariant
    STB8(0, 0, 0); STB8(0, 1, 0); STB8(0, 2, 0); STB8(0, 3, 0); STA8(0, 0, 0);
    STA8(0, 1, 0); STA8(0, 2, 0); STA8(0, 3, 0);
    asm volatile("s_waitcnt vmcnt(3)" ::: "memory");        // B0..B3,A0 landed
    __builtin_amdgcn_s_barrier();

    for (int k = 0; k < 7; k++) {
        int s = k & 1, o = s ^ 1, kt = k + 1;
        const unsigned short* As_s = &As[s][0];
        const unsigned short* Bs_s = &Bs[s][0];
        PHASE8(0, { STB8(o, 0, kt); STB8(o, 1, kt); STB8(o, 2, kt); STB8(o, 3, kt); STA8(o, 0, kt); },
               asm volatile("s_waitcnt vmcnt(7)" ::: "memory"));
        PHASE8(1, { STA8(o, 1, kt); STA8(o, 2, kt); STA8(o, 3, kt); },
               asm volatile("s_waitcnt vmcnt(8)" ::: "memory"));
        PHASE8(2, {}, (void)0);
        PHASE8(3, {}, asm volatile("s_waitcnt vmcnt(3)" ::: "memory"));
    }
    {   // tail K-tile 7 (slot 1): no staging; drain 2 -> 1 -> 0 (all long-issued)
        const unsigned short* As_s = &As[1][0];
        const unsigned short* Bs_s = &Bs[1][0];
        PHASE8(0, {}, asm volatile("s_waitcnt vmcnt(2)" ::: "memory"));
        PHASE8(1, {}, asm volatile("s_waitcnt vmcnt(1)" ::: "memory"));
        PHASE8(2, {}, asm volatile("s_waitcnt vmcnt(0)" ::: "memory"));
        PHASE8(3, {}, (void)0);
    }
#undef PHASE8
#undef STA8
#undef STB8

    int mat = colbase >> 9;
    int h = (colbase >> 6) & 7;
    int b_idx = mb >> 1;
    const float qscale = 0.06375873f;   // log2(e)/sqrt(512): scale + exp->exp2 fold

    if (swapQK) {
        // swapped: acc[mi][n][r] -> d = n*16+quad*4+r, s = (mb&1)*256+wr*128+mi*16+l16
        unsigned short* op = (mat == 0) ? Qo : Ko;
        float sc = (mat == 0) ? qscale : 1.0f;
#pragma unroll
        for (int mi = 0; mi < 8; mi++)
#pragma unroll
            for (int n = 0; n < 4; n++) {
                int s_ = (mb & 1) * 256 + wr * 128 + mi * 16 + l16;
                int d0 = n * 16 + quad * 4;
                ushort4 pk;
                pk.x = f2bf(acc[mi][n][0] * sc);
                pk.y = f2bf(acc[mi][n][1] * sc);
                pk.z = f2bf(acc[mi][n][2] * sc);
                pk.w = f2bf(acc[mi][n][3] * sc);
                *(ushort4*)&op[(size_t)((b_idx * Hn + h) * Sn + s_) * Dn + d0] = pk;
            }
    } else {
        // unswapped: V transposed Vt[b][h][d][s], packed along s
#pragma unroll
        for (int mi = 0; mi < 8; mi++)
#pragma unroll
            for (int n = 0; n < 4; n++) {
                int d = n * 16 + l16;
                int srow = (mb & 1) * 256 + wr * 128 + mi * 16 + quad * 4;
                ushort4 pk;
                pk.x = f2bf(acc[mi][n][0]); pk.y = f2bf(acc[mi][n][1]);
                pk.z = f2bf(acc[mi][n][2]); pk.w = f2bf(acc[mi][n][3]);
                *(ushort4*)&Vt[(size_t)((b_idx * Hn + h) * Dn + d) * Sn + srow] = pk;
            }
    }
}

// ---------------------------------------------------------------- attention
// grid (2 qhalf, 512 bh), 256 thr (4 waves). Wave w owns strips i=0..3
// (16 queries each of this block's 256-query half). S^T form:
//   sacc = mfma(A=K_frag, B=Q_frag): C rows = keys (key = n*16+quad*4+r),
//   col = query l16.
//   -> P packed uint2 -> b64 LDS writes, logical [query][key] swizzled
//   -> PV: A=P (b128), B=V^T rows; C rows = queries, cols = d.
__global__ __launch_bounds__(256) void attn_kernel(const unsigned short* __restrict__ Q,
                                                   const unsigned short* __restrict__ K,
                                                   const unsigned short* __restrict__ Vt,
                                                   const float* __restrict__ mask,
                                                   unsigned short* __restrict__ attn) {
    int qhalf = blockIdx.x, bh = blockIdx.y;
    int h = bh & 7, b = bh >> 3;
    __shared__ __align__(16) unsigned short Kc[64 * 64];        // [key][d] swizzled
    __shared__ __align__(16) unsigned short Vc[64 * 64];        // [d][key] swizzled
    __shared__ __align__(16) unsigned short Ps[4][4 * 16 * 64]; // [wave][strip][q][key]
    __shared__ float maskv[64];
    int tid = threadIdx.x;
    int w = tid >> 6, lane = tid & 63, quad = lane >> 4, l16 = lane & 15;
    int l7 = l16 & 7;

    const unsigned short* Qg = Q + (size_t)(bh * Sn + qhalf * 256) * Dn;
    const unsigned short* Kg = K + (size_t)(bh * Sn) * Dn;
    const unsigned short* Vg = Vt + (size_t)(bh * Dn) * Sn;

    // Q frags (A/B lane layouts identical), registers, whole kernel
    s8v aq[4][2];
#pragma unroll
    for (int i = 0; i < 4; i++)
#pragma unroll
        for (int ks = 0; ks < 2; ks++)
            aq[i][ks] = *(const s8v*)&Qg[((w * 4 + i) * 16 + l16) * 64 + ks * 32 + quad * 8];

    f4v acc[4][4];
    float psum[4] = {0.f, 0.f, 0.f, 0.f};
#pragma unroll
    for (int i = 0; i < 4; i++)
#pragma unroll
        for (int n = 0; n < 4; n++) acc[i][n] = (f4v){0.f, 0.f, 0.f, 0.f};

    // staging: each async16 covers 8 rows (64 lanes x 16B); wave w rows w*16..+15
    int srow0 = w * 16 + (lane >> 3);
    int srow1 = srow0 + 8;
    int gseg0 = ((lane & 7) ^ (srow0 & 7)) * 8;   // global seg so LDS[p] = g ^ (row&7)
    int gseg1 = ((lane & 7) ^ (srow1 & 7)) * 8;
    unsigned short* kdst0 = &Kc[(w * 16) * 64];
    unsigned short* kdst1 = &Kc[(w * 16 + 8) * 64];
    unsigned short* vdst0 = &Vc[(w * 16) * 64];
    unsigned short* vdst1 = &Vc[(w * 16 + 8) * 64];

    unsigned short* Pw = Ps[w];
    int wbase = l16 * 64 + (quad & 1) * 4;        // P write: row l16 + sub-offset
    const float cM = -1.4426950409e10f;           // -1e10 * log2(e)

    for (int kc = 0; kc < 8; kc++) {
        __syncthreads();                          // all waves done with prev chunk
        async16(Kg + (kc * 64 + srow0) * 64 + gseg0, kdst0);
        async16(Kg + (kc * 64 + srow1) * 64 + gseg1, kdst1);
        async16(Vg + srow0 * 512 + kc * 64 + gseg0, vdst0);
        async16(Vg + srow1 * 512 + kc * 64 + gseg1, vdst1);
        if (w == 0) async4(mask + b * Sn + kc * 64 + lane, maskv);
        __syncthreads();                          // vmcnt drained -> chunk ready

        // ---- S^T = K Q^T per key-tile n; bk shared across all 4 strips ----
#pragma unroll
        for (int n = 0; n < 4; n++) {
            s8v bk0 = *(const s8v*)&Kc[(n * 16 + l16) * 64 + (quad ^ l7) * 8];
            s8v bk1 = *(const s8v*)&Kc[(n * 16 + l16) * 64 + ((4 + quad) ^ l7) * 8];
            float4 mv = *(const float4*)&maskv[n * 16 + quad * 4];
            float m0 = mv.x * cM, m1 = mv.y * cM, m2 = mv.z * cM, m3 = mv.w * cM;
            int wseg = ((n * 2 + (quad >> 1)) ^ l7) * 8;
            f4v sacc[4];
#pragma unroll
            for (int i = 0; i < 4; i++) {
                sacc[i] = __builtin_amdgcn_mfma_f32_16x16x32_bf16(
                              bk0, aq[i][0], (f4v){0.f, 0.f, 0.f, 0.f}, 0, 0, 0);
                sacc[i] = __builtin_amdgcn_mfma_f32_16x16x32_bf16(
                              bk1, aq[i][1], sacc[i], 0, 0, 0);
            }
#pragma unroll
            for (int i = 0; i < 4; i++) {
                unsigned int u0 = __float_as_uint(__builtin_amdgcn_exp2f(sacc[i][0] + m0));
                unsigned int u1 = __float_as_uint(__builtin_amdgcn_exp2f(sacc[i][1] + m1));
                unsigned int u2 = __float_as_uint(__builtin_amdgcn_exp2f(sacc[i][2] + m2));
                unsigned int u3 = __float_as_uint(__builtin_amdgcn_exp2f(sacc[i][3] + m3));
                psum[i] += __uint_as_float(u0 & 0xffff0000u) + __uint_as_float(u1 & 0xffff0000u)
                         + __uint_as_float(u2 & 0xffff0000u) + __uint_as_float(u3 & 0xffff0000u);
                uint2 pk;
                pk.x = (u0 >> 16) | (u1 & 0xffff0000u);
                pk.y = (u2 >> 16) | (u3 & 0xffff0000u);
                *(uint2*)&Pw[(i << 10) + wbase + wseg] = pk;
            }
        }
        // Ps is wave-private; DS ops in-order per wave -> no barrier needed.

        // ---- O += P V : ks-outer, ap/bv shared across strips ----
#pragma unroll
        for (int ks = 0; ks < 2; ks++) {
            int sw = ((ks * 4 + quad) ^ l7) * 8;
            s8v ap[4];
#pragma unroll
            for (int i = 0; i < 4; i++)
                ap[i] = *(const s8v*)&Pw[(i << 10) + l16 * 64 + sw];
#pragma unroll
            for (int n = 0; n < 4; n++) {
                s8v bv = *(const s8v*)&Vc[(n * 16 + l16) * 64 + sw];
#pragma unroll
                for (int i = 0; i < 4; i++)
                    acc[i][n] = __builtin_amdgcn_mfma_f32_16x16x32_bf16(ap[i], bv, acc[i][n], 0, 0, 0);
            }
        }
    }

    // deferred normalization: psum[i] is quad-partial for query l16
#pragma unroll
    for (int i = 0; i < 4; i++) {
        float s = psum[i];
        s += __shfl_xor(s, 16, 64);
        s += __shfl_xor(s, 32, 64);               // every lane: total for query l16
        float inv[4];
#pragma unroll
        for (int r = 0; r < 4; r++)
            inv[r] = 1.0f / __shfl(s, quad * 4 + r, 64);
#pragma unroll
        for (int n = 0; n < 4; n++)
#pragma unroll
            for (int r = 0; r < 4; r++) {
                int query = qhalf * 256 + (w * 4 + i) * 16 + quad * 4 + r;
                int col = h * 64 + n * 16 + l16;
                attn[(size_t)(b * Sn + query) * (Hn * Dn) + col] = f2bf(acc[i][n][r] * inv[r]);
            }
    }
}

// ---------------------------------------------------------------- outproj
// out[32768,512] = attn[32768,512] x WOt^T, fp32 out. grid (4 nb, 256 mb).
// Counted-vmcnt dbuf + swapped mfma(B,A): lane holds 4 consecutive cols.
__global__ __launch_bounds__(256) void outproj(const unsigned short* __restrict__ attn,
                                               const unsigned short* __restrict__ WOt,
                                               float* __restrict__ out) {
    int nb = blockIdx.x, mb = blockIdx.y;
    __shared__ __align__(16) unsigned short At[2][128 * 64];
    __shared__ __align__(16) unsigned short Bt[2][128 * 64];
    int tid = threadIdx.x;
    int w = tid >> 6, lane = tid & 63, quad = lane >> 4, l16 = lane & 15;
    int wr = w >> 1, wc = w & 1;
    int lrow = lane >> 3;
    int lseg = ((lane & 7) ^ lrow) * 8;

    f4v acc[4][4];
#pragma unroll
    for (int i = 0; i < 4; i++)
#pragma unroll
        for (int n = 0; n < 4; n++) acc[i][n] = (f4v){0.f, 0.f, 0.f, 0.f};

    const unsigned short* Ag = attn + (size_t)mb * 128 * 512;
    const unsigned short* Bg = WOt + (size_t)nb * 128 * 512;

    // prologue: stage chunk 0
#pragma unroll
    for (int i = 0; i < 4; i++) {
        int r0 = w * 32 + i * 8;
        async16(Ag + (r0 + lrow) * 512 + lseg, &At[0][r0 * 64]);
        async16(Bg + (r0 + lrow) * 512 + lseg, &Bt[0][r0 * 64]);
    }

    int cur = 0;
    for (int kc = 0; kc < 8; kc++) {
        if (kc < 7) {
            int nxt = cur ^ 1;
#pragma unroll
            for (int i = 0; i < 4; i++) {
                int r0 = w * 32 + i * 8;
                async16(Ag + (r0 + lrow) * 512 + (kc + 1) * 64 + lseg, &At[nxt][r0 * 64]);
                async16(Bg + (r0 + lrow) * 512 + (kc + 1) * 64 + lseg, &Bt[nxt][r0 * 64]);
            }
            asm volatile("s_waitcnt vmcnt(8)" ::: "memory");
        } else {
            asm volatile("s_waitcnt vmcnt(0)" ::: "memory");
        }
        __builtin_amdgcn_s_barrier();

#pragma unroll
        for (int ks = 0; ks < 2; ks++) {
            int sw = ((ks * 4 + quad) ^ (l16 & 7)) * 8;
            s8v a[4], b[4];
#pragma unroll
            for (int i = 0; i < 4; i++)
                a[i] = *(const s8v*)&At[cur][(wr * 64 + i * 16 + l16) * 64 + sw];
#pragma unroll
            for (int n = 0; n < 4; n++)
                b[n] = *(const s8v*)&Bt[cur][(wc * 64 + n * 16 + l16) * 64 + sw];
#pragma unroll
            for (int i = 0; i < 4; i++)
#pragma unroll
                for (int n = 0; n < 4; n++)
                    acc[i][n] = __builtin_amdgcn_mfma_f32_16x16x32_bf16(b[n], a[i], acc[i][n], 0, 0, 0);
        }
        asm volatile("s_waitcnt lgkmcnt(0)" ::: "memory");
        __builtin_amdgcn_s_barrier();
        cur ^= 1;
    }
    // swapped: acc[i][n][r] -> row = mb*128+wr*64+i*16+l16, col = nb*128+wc*64+n*16+quad*4+r
#pragma unroll
    for (int i = 0; i < 4; i++)
#pragma unroll
        for (int n = 0; n < 4; n++) {
            int row = mb * 128 + wr * 64 + i * 16 + l16;
            int col = nb * 128 + wc * 64 + n * 16 + quad * 4;
            float4 o;
            o.x = acc[i][n][0]; o.y = acc[i][n][1];
            o.z = acc[i][n][2]; o.w = acc[i][n][3];
            *(float4*)&out[(size_t)row * 512 + col] = o;
        }
}

// ---------------------------------------------------------------- launch
extern "C" void kernel_launch(void* const* d_in, const int* in_sizes, int n_in,
                              void* d_out, int out_size, void* d_ws, size_t ws_size,
                              hipStream_t stream) {
    const float* x    = (const float*)d_in[0];
    const float* mask = (const float*)d_in[1];
    const float* WQ   = (const float*)d_in[2];
    const float* WK   = (const float*)d_in[3];
    const float* WV   = (const float*)d_in[4];
    const float* BE   = (const float*)d_in[5];
    const float* WO   = (const float*)d_in[6];
    float* out = (float*)d_out;

    char* ws = (char*)d_ws;
    unsigned short* hbf   = (unsigned short*)(ws);                 // 33554432 B
    unsigned short* Wqkvt = (unsigned short*)(ws + 33554432);      //  1572864 B
    unsigned short* WOt   = (unsigned short*)(ws + 35127296);      //   524288 B
    unsigned short* Qp    = (unsigned short*)(ws + 35651584);      // 33554432 B
    unsigned short* Kp    = (unsigned short*)(ws + 69206016);      // 33554432 B
    unsigned short* Vtp   = (unsigned short*)(ws + 102760448);     // 33554432 B
    unsigned short* attnp = (unsigned short*)(ws + 136314880);     // 33554432 B

    prep_h<<<16384, 256, 0, stream>>>(x, BE, hbf);
    prep_w<<<4096, 256, 0, stream>>>(WQ, WK, WV, WO, Wqkvt, WOt);
    qkv_gemm<<<dim3(6, 128), 512, 0, stream>>>(hbf, Wqkvt, Qp, Kp, Vtp);
    attn_kernel<<<dim3(2, 512), 256, 0, stream>>>(Qp, Kp, Vtp, mask, attnp);
    outproj<<<dim3(4, 256), 256, 0, stream>>>(attnp, WOt, out);
}